// Round 1
// 124.980 us; speedup vs baseline: 1.0141x; 1.0141x over previous
//
#include <hip/hip_runtime.h>

#define HSZ 256
#define WSZ 256
#define NFC 64
#define PLANE (HSZ * WSZ)

typedef __attribute__((ext_vector_type(8))) short short8;
typedef __attribute__((ext_vector_type(4))) float f32x4;

__device__ inline unsigned short f2bf(float f) {
    unsigned u = __builtin_bit_cast(unsigned, f);
    return (unsigned short)((u + 0x7fffu + ((u >> 16) & 1u)) >> 16);   // RTNE
}

// ============================================================================
// Fully fused dynamic-filter kernel. One 16x16-px tile per block, 256 threads,
// grid (16,16,B) = 512 blocks. NO workspace use (avoids ws re-poison fills).
//
// LDS layout (bytes), phase-overlaid:
//   [0,     36288) : xs  - i_t tile, 324 sp x 56 shorts (48 data + 8 pad)
//                    hs  - later: h tile double buffer, 2 x 8ch x 18 x 24 f32
//   [36288, 45504) : lw  - conv_w transposed [k432][9] bf16 (7776 B)
//                    lf  - later: filters [9][16][16] f32 (9216 B)
// Total 45504 B -> 3 blocks/CU possible; grid gives 2 resident.
//
// Phases: stage(xs+lw) | B1 | gather wf + 56 MFMA | B2 | lf write (+pre-issue
// h cg0 loads) | B3 | flt->regs + hs buf0 write | B4 | 8x { load cg+1,
// compute cg, write buf^1, sync }.
// xs ch-stride 56 shorts => A-frag ds_read_b128 2-way banked (free).
// ============================================================================
__global__ __launch_bounds__(256, 3) void fused_dynfilter_v2(
    const float* __restrict__ hbuf,
    const float* __restrict__ i_t,
    const float* __restrict__ wbuf,
    const float* __restrict__ bias,
    float* __restrict__ out)
{
    __shared__ __align__(16) unsigned char smem[45504];
    unsigned short* const xs = (unsigned short*)smem;            // 324 x 56
    unsigned short* const lw = (unsigned short*)(smem + 36288);  // 432 x 9
    float* const lf = (float*)(smem + 36288);                    // 9 x 16 x 16
    float* const hs = (float*)smem;                              // 2 x 3456 f32

    const int tid  = threadIdx.x;
    const int X0   = blockIdx.x * 16;
    const int Y0   = blockIdx.y * 16;
    const int b    = blockIdx.z;
    const int lane = tid & 63;
    const int l15  = lane & 15;     // A: px col / B,C: oc
    const int kg   = lane >> 4;     // k-subgroup
    const int wv   = tid >> 6;      // wave -> px rows 4wv..4wv+3

    const float bv = (l15 < 9) ? bias[l15] : 0.f;
    const float* itb = i_t + (size_t)b * 3 * (PLANE * 16);

    // ---- phase 0a: stage shuffled i_t tile (3888 float4 jobs, 2 batches of 8)
    {
#pragma unroll
        for (int g = 0; g < 2; ++g) {
            float4 lreg[8]; int sdst[8];
#pragma unroll
            for (int k = 0; k < 8; ++k) {
                const int v = tid + 256 * (g * 8 + k);
                const int sp = v / 12, t = v - sp * 12;          // t = c3*4+fy
                const int c3 = t >> 2, fy = t & 3;
                const int ly = sp / 18, lx = sp - ly * 18;
                const int Y = Y0 - 1 + ly, X = X0 - 1 + lx;
                float4 val = make_float4(0.f, 0.f, 0.f, 0.f);
                if (v < 3888 && (unsigned)Y < HSZ && (unsigned)X < WSZ)
                    val = *(const float4*)(itb + ((size_t)c3 * 1024 + (4 * Y + fy)) * 1024 + 4 * X);
                lreg[k] = val;
                sdst[k] = (v < 3888) ? (sp * 56 + t * 4) : -1;
            }
#pragma unroll
            for (int k = 0; k < 8; ++k)
                if (sdst[k] >= 0) {
                    ushort4 u{f2bf(lreg[k].x), f2bf(lreg[k].y), f2bf(lreg[k].z), f2bf(lreg[k].w)};
                    *(ushort4*)(xs + sdst[k]) = u;
                }
        }
    }

    // ---- phase 0b: stage conv_w transposed to lw[k432*9 + oc] bf16
    {
        float wreg[16]; int wdst[16];
#pragma unroll
        for (int k = 0; k < 16; ++k) {
            const int v = tid + 256 * k;
            float w = 0.f; int d = -1;
            if (v < 3888) {
                const int oc = v / 432, kc = v - 432 * oc;       // kc = kk*48+ic
                const int kk = kc / 48, ic = kc - 48 * kk;
                w = wbuf[oc * 432 + ic * 9 + kk];
                d = kc * 9 + oc;
            }
            wreg[k] = w; wdst[k] = d;
        }
#pragma unroll
        for (int k = 0; k < 16; ++k)
            if (wdst[k] >= 0) lw[wdst[k]] = f2bf(wreg[k]);
    }

    __syncthreads();   // B1: xs + lw ready

    // ---- phase 1: gather B-fragments (no divisions: k linear in lw index)
    short8 wf[14];
    {
        const int base = kg * 72 + l15;                          // (kg*8)*9 + oc
#pragma unroll
        for (int kb = 0; kb < 14; ++kb) {
            unsigned short v8[8];
#pragma unroll
            for (int j = 0; j < 8; ++j)
                v8[j] = lw[base + (kb * 32 + j) * 9];
            if (kb == 13 && kg >= 2) {                           // k >= 432 -> 0
#pragma unroll
                for (int j = 0; j < 8; ++j) v8[j] = 0;
            }
            short8 w;
#pragma unroll
            for (int j = 0; j < 8; ++j) w[j] = (short)v8[j];
            wf[kb] = w;
        }
    }

    // ---- MFMA: 14 K-blocks x 4 row-tiles (y = 4wv+t)
    f32x4 acc[4];
#pragma unroll
    for (int t = 0; t < 4; ++t) acc[t] = (f32x4){0.f, 0.f, 0.f, 0.f};

#pragma unroll
    for (int kb = 0; kb < 14; ++kb) {
        const int k0 = kb * 32 + kg * 8;
        int off = 0;
        if (k0 < 432) {
            const int kk = k0 / 48, ic0 = k0 - 48 * kk;
            const int ky = kk / 3, kx = kk - 3 * ky;
            off = ((4 * wv + ky) * 18 + l15 + kx) * 56 + ic0;    // 16B-aligned
        }
        const unsigned short* ap = xs + off;
#pragma unroll
        for (int t = 0; t < 4; ++t) {
            short8 a = *(const short8*)(ap + t * 1008);          // +1 px row = 18*56
            acc[t] = __builtin_amdgcn_mfma_f32_16x16x32_bf16(a, wf[kb], acc[t], 0, 0, 0);
        }
    }

    __syncthreads();   // B2: all xs/lw reads done (hs/lf may overwrite)

    // ---- phase 2: filters -> lf (relu + bias)
    if (l15 < 9) {
#pragma unroll
        for (int t = 0; t < 4; ++t) {
            const int py = 4 * wv + t;
#pragma unroll
            for (int r = 0; r < 4; ++r)
                lf[l15 * 256 + py * 16 + (kg * 4 + r)] = fmaxf(acc[t][r] + bv, 0.f);
        }
    }

    const int pq  = tid & 3;          // px group of 4 (x = X0+pq*4..+3)
    const int pyA = (tid >> 2) & 15;
    const int clo = tid >> 6;         // 0..3

    // pre-issue h loads for cg = 0 (in flight across B3)
    float4 h0reg[4]; int h0dst[4];
    {
        const float* hp = hbuf + (size_t)b * NFC * PLANE;
#pragma unroll
        for (int k = 0; k < 4; ++k) {
            const int v = tid + 256 * k;
            float4 val = make_float4(0.f, 0.f, 0.f, 0.f);
            int d = -1;
            if (v < 864) {
                const int c = v / 108, r = v - 108 * c;
                const int row = r / 6, xq = r - 6 * row;
                const int Y = Y0 - 1 + row, X4 = X0 - 4 + xq * 4;
                if ((unsigned)Y < HSZ && (unsigned)X4 < WSZ)
                    val = *(const float4*)(hp + (size_t)c * PLANE + (size_t)Y * WSZ + X4);
                d = c * 432 + row * 24 + xq * 4;
            }
            h0reg[k] = val; h0dst[k] = d;
        }
    }

    __syncthreads();   // B3: lf ready

    // per-pixel filters into registers (lf never overwritten below)
    float4 flt[9];
#pragma unroll
    for (int oc = 0; oc < 9; ++oc)
        flt[oc] = *(const float4*)(lf + oc * 256 + pyA * 16 + pq * 4);

#pragma unroll
    for (int k = 0; k < 4; ++k)
        if (h0dst[k] >= 0) *(float4*)(hs + h0dst[k]) = h0reg[k];

    __syncthreads();   // B4: hs buf0 ready

    // ---- 8 channel groups, double-buffered hs, 1 barrier per group
#pragma unroll
    for (int cg = 0; cg < 8; ++cg) {
        const int buf = cg & 1;

        float4 nreg[4]; int ndst[4];
        if (cg < 7) {
            const float* hp = hbuf + ((size_t)b * NFC + (cg + 1) * 8) * PLANE;
#pragma unroll
            for (int k = 0; k < 4; ++k) {
                const int v = tid + 256 * k;
                float4 val = make_float4(0.f, 0.f, 0.f, 0.f);
                int d = -1;
                if (v < 864) {
                    const int c = v / 108, r = v - 108 * c;
                    const int row = r / 6, xq = r - 6 * row;
                    const int Y = Y0 - 1 + row, X4 = X0 - 4 + xq * 4;
                    if ((unsigned)Y < HSZ && (unsigned)X4 < WSZ)
                        val = *(const float4*)(hp + (size_t)c * PLANE + (size_t)Y * WSZ + X4);
                    d = c * 432 + row * 24 + xq * 4;
                }
                nreg[k] = val; ndst[k] = d;
            }
        }

        float a[2][4];
#pragma unroll
        for (int cc = 0; cc < 2; ++cc)
#pragma unroll
            for (int j = 0; j < 4; ++j) a[cc][j] = 0.f;

#pragma unroll
        for (int cc = 0; cc < 2; ++cc) {
            const float* pl = hs + buf * 3456 + (clo * 2 + cc) * 432;
#pragma unroll
            for (int ky = 0; ky < 3; ++ky) {
                const float* rp = pl + (pyA + ky) * 24 + pq * 4;   // col 0 = X0-4
                const float4 w0 = *(const float4*)rp;
                const float4 w1 = *(const float4*)(rp + 4);
                const float w8 = rp[8];
                const float vs[9] = {w0.x, w0.y, w0.z, w0.w, w1.x, w1.y, w1.z, w1.w, w8};
#pragma unroll
                for (int kx = 0; kx < 3; ++kx)
#pragma unroll
                    for (int j = 0; j < 4; ++j)
                        a[cc][j] = fmaf(vs[3 + kx + j], flt[ky * 3 + kx][j], a[cc][j]);
            }
        }

#pragma unroll
        for (int cc = 0; cc < 2; ++cc) {
            const int ch = cg * 8 + clo * 2 + cc;
            *(float4*)(out + ((size_t)b * NFC + ch) * PLANE
                           + (size_t)(Y0 + pyA) * WSZ + X0 + pq * 4)
                = make_float4(a[cc][0], a[cc][1], a[cc][2], a[cc][3]);
        }

        if (cg < 7) {
            float* hb = hs + (buf ^ 1) * 3456;
#pragma unroll
            for (int k = 0; k < 4; ++k)
                if (ndst[k] >= 0) *(float4*)(hb + ndst[k]) = nreg[k];
            __syncthreads();   // buf^1 ready for next group
        }
    }
}

extern "C" void kernel_launch(void* const* d_in, const int* in_sizes, int n_in,
                              void* d_out, int out_size, void* d_ws, size_t ws_size,
                              hipStream_t stream) {
    const float* h      = (const float*)d_in[0];
    const float* i_t    = (const float*)d_in[1];
    const float* conv_w = (const float*)d_in[2];
    const float* conv_b = (const float*)d_in[3];
    float* out = (float*)d_out;

    const int B = in_sizes[0] / (NFC * PLANE);
    dim3 grid(WSZ / 16, HSZ / 16, B);
    fused_dynfilter_v2<<<grid, 256, 0, stream>>>(h, i_t, conv_w, conv_b, out);
}

// Round 2
// 116.923 us; speedup vs baseline: 1.0840x; 1.0689x over previous
//
#include <hip/hip_runtime.h>

#define HSZ 256
#define WSZ 256
#define NFC 64
#define PLANE (HSZ * WSZ)

typedef __attribute__((ext_vector_type(8))) short short8;
typedef __attribute__((ext_vector_type(4))) float f32x4;

__device__ inline unsigned short f2bf(float f) {
    unsigned u = __builtin_bit_cast(unsigned, f);
    return (unsigned short)((u + 0x7fffu + ((u >> 16) & 1u)) >> 16);   // RTNE
}

// ============================================================================
// Fused dynamic-filter kernel, v3: 16(x) x 8(y) px tile, 256 threads,
// grid (16,32,B) = 1024 blocks -> 4 blocks/CU (vs v2's 2). No workspace.
//
// LDS (28096 B -> 5 blocks/CU allowed), phase-overlaid:
//   [0,     20160) : xs  - i_t tile, 180 sp (10y x 18x) x 56 shorts (48+8 pad)
//                    hs  - later: h double buffer, 2 x 8ch x 10 rows x 24 cols f32
//   [20160, 28096) : lwT - conv_w transposed [oc][k=kk*48+ic] bf16, stride 440
//                    lf  - later: filters [9][8][16] f32
//
// B-fragment gather = 14 x ds_read_b128 (stride 440 sh = 220 w, gcd 4 -> 2-way).
// XCD swizzle: 8 contiguous tile-rows per XCD chunk for halo L2 reuse.
// ============================================================================
__global__ __launch_bounds__(256, 4) void fused_dynfilter_v3(
    const float* __restrict__ hbuf,
    const float* __restrict__ i_t,
    const float* __restrict__ wbuf,
    const float* __restrict__ bias,
    float* __restrict__ out)
{
    __shared__ __align__(16) unsigned char smem[28096];
    unsigned short* const xs  = (unsigned short*)smem;            // 180 x 56
    unsigned short* const lwT = (unsigned short*)(smem + 20160);  // 9 x 440
    float* const lf = (float*)(smem + 20160);                     // 9 x 8 x 16
    float* const hs = (float*)smem;                               // 2 x 8 x 240

    const int tid = threadIdx.x;

    // XCD-aware bijective block swizzle (total = 512*B, divisible by 8)
    const int lin = blockIdx.x + 16 * (blockIdx.y + 32 * blockIdx.z);
    const int q   = ((int)gridDim.z * 512) >> 3;
    const int nid = (lin & 7) * q + (lin >> 3);
    const int b   = nid >> 9;
    const int rem = nid & 511;
    const int X0  = (rem & 15) * 16;
    const int Y0  = (rem >> 4) * 8;

    const int lane = tid & 63;
    const int l15  = lane & 15;     // A: px col / B,C: oc
    const int kg   = lane >> 4;     // k-subgroup
    const int wv   = tid >> 6;      // wave -> px rows 2wv, 2wv+1

    const float bv = (l15 < 9) ? bias[l15] : 0.f;
    const float* itb = i_t + (size_t)b * 3 * (PLANE * 16);

    // ---- phase 0a: stage shuffled i_t tile (2160 float4 jobs, 9 rounds)
    {
        float4 lreg[9]; int sdst[9];
#pragma unroll
        for (int k = 0; k < 9; ++k) {
            const int v = tid + 256 * k;
            const int sp = v / 12, t = v - sp * 12;          // t = c3*4+fy
            const int c3 = t >> 2, fy = t & 3;
            const int ly = sp / 18, lx = sp - ly * 18;
            const int Y = Y0 - 1 + ly, X = X0 - 1 + lx;
            float4 val = make_float4(0.f, 0.f, 0.f, 0.f);
            if (v < 2160 && (unsigned)Y < HSZ && (unsigned)X < WSZ)
                val = *(const float4*)(itb + ((size_t)c3 * 1024 + (4 * Y + fy)) * 1024 + 4 * X);
            lreg[k] = val;
            sdst[k] = (v < 2160) ? (sp * 56 + t * 4) : -1;
        }
#pragma unroll
        for (int k = 0; k < 9; ++k)
            if (sdst[k] >= 0) {
                ushort4 u{f2bf(lreg[k].x), f2bf(lreg[k].y), f2bf(lreg[k].z), f2bf(lreg[k].w)};
                *(ushort4*)(xs + sdst[k]) = u;
            }
    }

    // ---- phase 0b: stage conv_w -> lwT[oc*440 + kk*48+ic], coalesced f4 loads
    {
        float4 wr[4];
#pragma unroll
        for (int k = 0; k < 4; ++k) {
            const int v = tid + 256 * k;
            wr[k] = (v < 972) ? *(const float4*)(wbuf + (size_t)v * 4)
                              : make_float4(0.f, 0.f, 0.f, 0.f);
        }
#pragma unroll
        for (int k = 0; k < 4; ++k) {
            const int v = tid + 256 * k;
            if (v < 972) {
                const float e[4] = {wr[k].x, wr[k].y, wr[k].z, wr[k].w};
#pragma unroll
                for (int j = 0; j < 4; ++j) {
                    const int n  = v * 4 + j;
                    const int oc = n / 432;
                    const int r  = n - 432 * oc;
                    const int ic = r / 9;
                    const int kk = r - 9 * ic;
                    lwT[oc * 440 + kk * 48 + ic] = f2bf(e[j]);
                }
            }
        }
    }

    __syncthreads();   // B1: xs + lwT ready

    // ---- B-fragments: 14 x ds_read_b128 (k = kb*32 + kg*8 + j, contiguous)
    short8 wf[14];
    {
        const unsigned short* lwb = lwT + l15 * 440 + kg * 8;
#pragma unroll
        for (int kb = 0; kb < 14; ++kb) {
            short8 w = {0, 0, 0, 0, 0, 0, 0, 0};
            if (l15 < 9 && !(kb == 13 && kg >= 2))
                w = *(const short8*)(lwb + kb * 32);
            wf[kb] = w;
        }
    }

    // ---- MFMA: 14 K-blocks x 2 row-tiles (px rows 2wv, 2wv+1)
    f32x4 acc0 = {0.f, 0.f, 0.f, 0.f}, acc1 = acc0;
#pragma unroll
    for (int kb = 0; kb < 14; ++kb) {
        const int k0 = kb * 32 + kg * 8;
        int off = 0;
        if (k0 < 432) {
            const int kk = k0 / 48, ic0 = k0 - 48 * kk;
            const int ky = kk / 3, kx = kk - 3 * ky;
            off = ((2 * wv + ky) * 18 + l15 + kx) * 56 + ic0;    // 16B-aligned
        }
        short8 a0 = *(const short8*)(xs + off);
        short8 a1 = *(const short8*)(xs + off + 1008);           // +1 px row (18*56)
        acc0 = __builtin_amdgcn_mfma_f32_16x16x32_bf16(a0, wf[kb], acc0, 0, 0, 0);
        acc1 = __builtin_amdgcn_mfma_f32_16x16x32_bf16(a1, wf[kb], acc1, 0, 0, 0);
    }

    __syncthreads();   // B2: xs/lwT reads done (hs/lf may overwrite)

    // ---- filters -> lf (relu + bias)
    if (l15 < 9) {
#pragma unroll
        for (int t = 0; t < 2; ++t) {
            const int py = 2 * wv + t;
            const f32x4 A = t ? acc1 : acc0;
#pragma unroll
            for (int r = 0; r < 4; ++r)
                lf[l15 * 128 + py * 16 + (kg * 4 + r)] = fmaxf(A[r] + bv, 0.f);
        }
    }

    const int pq  = tid & 3;          // px group of 4 (x = X0+pq*4..+3)
    const int pyA = (tid >> 2) & 7;   // px row
    const int clo = tid >> 5;         // 0..7: channel within group

    // pre-issue h loads for cg = 0 (in flight across B3)
    float4 h0reg[2]; int h0dst[2];
    {
        const float* hp = hbuf + (size_t)b * NFC * PLANE;
#pragma unroll
        for (int k = 0; k < 2; ++k) {
            const int v = tid + 256 * k;
            float4 val = make_float4(0.f, 0.f, 0.f, 0.f);
            int d = -1;
            if (v < 480) {
                const int c = v / 60, r = v - 60 * c;
                const int row = r / 6, xq = r - 6 * row;
                const int Y = Y0 - 1 + row, X4 = X0 - 4 + xq * 4;
                if ((unsigned)Y < HSZ && (unsigned)X4 < WSZ)
                    val = *(const float4*)(hp + (size_t)c * PLANE + (size_t)Y * WSZ + X4);
                d = c * 240 + row * 24 + xq * 4;
            }
            h0reg[k] = val; h0dst[k] = d;
        }
    }

    __syncthreads();   // B3: lf ready

    // per-pixel filters into registers
    float4 flt[9];
#pragma unroll
    for (int oc = 0; oc < 9; ++oc)
        flt[oc] = *(const float4*)(lf + oc * 128 + pyA * 16 + pq * 4);

#pragma unroll
    for (int k = 0; k < 2; ++k)
        if (h0dst[k] >= 0) *(float4*)(hs + h0dst[k]) = h0reg[k];

    __syncthreads();   // B4: hs buf0 ready

    // ---- 8 channel groups, double-buffered hs, 1 barrier per group
#pragma unroll
    for (int cg = 0; cg < 8; ++cg) {
        const int buf = cg & 1;

        float4 nreg[2]; int ndst[2];
        if (cg < 7) {
            const float* hp = hbuf + ((size_t)b * NFC + (cg + 1) * 8) * PLANE;
#pragma unroll
            for (int k = 0; k < 2; ++k) {
                const int v = tid + 256 * k;
                float4 val = make_float4(0.f, 0.f, 0.f, 0.f);
                int d = -1;
                if (v < 480) {
                    const int c = v / 60, r = v - 60 * c;
                    const int row = r / 6, xq = r - 6 * row;
                    const int Y = Y0 - 1 + row, X4 = X0 - 4 + xq * 4;
                    if ((unsigned)Y < HSZ && (unsigned)X4 < WSZ)
                        val = *(const float4*)(hp + (size_t)c * PLANE + (size_t)Y * WSZ + X4);
                    d = c * 240 + row * 24 + xq * 4;
                }
                nreg[k] = val; ndst[k] = d;
            }
        }

        float a[4];
#pragma unroll
        for (int j = 0; j < 4; ++j) a[j] = 0.f;

        const float* pl = hs + buf * 1920 + clo * 240;
#pragma unroll
        for (int ky = 0; ky < 3; ++ky) {
            const float* rp = pl + (pyA + ky) * 24 + pq * 4;     // col 0 = X0-4
            const float4 w0 = *(const float4*)rp;
            const float4 w1 = *(const float4*)(rp + 4);
            const float  w8 = rp[8];
            const float vs[9] = {w0.x, w0.y, w0.z, w0.w, w1.x, w1.y, w1.z, w1.w, w8};
#pragma unroll
            for (int kx = 0; kx < 3; ++kx)
#pragma unroll
                for (int j = 0; j < 4; ++j)
                    a[j] = fmaf(vs[3 + kx + j], flt[ky * 3 + kx][j], a[j]);
        }

        const int ch = cg * 8 + clo;
        *(float4*)(out + ((size_t)b * NFC + ch) * PLANE
                       + (size_t)(Y0 + pyA) * WSZ + X0 + pq * 4)
            = make_float4(a[0], a[1], a[2], a[3]);

        if (cg < 7) {
            float* hb = hs + (buf ^ 1) * 1920;
#pragma unroll
            for (int k = 0; k < 2; ++k)
                if (ndst[k] >= 0) *(float4*)(hb + ndst[k]) = nreg[k];
            __syncthreads();   // buf^1 ready for next group
        }
    }
}

extern "C" void kernel_launch(void* const* d_in, const int* in_sizes, int n_in,
                              void* d_out, int out_size, void* d_ws, size_t ws_size,
                              hipStream_t stream) {
    const float* h      = (const float*)d_in[0];
    const float* i_t    = (const float*)d_in[1];
    const float* conv_w = (const float*)d_in[2];
    const float* conv_b = (const float*)d_in[3];
    float* out = (float*)d_out;

    const int B = in_sizes[0] / (NFC * PLANE);
    dim3 grid(WSZ / 16, HSZ / 8, B);
    fused_dynfilter_v3<<<grid, 256, 0, stream>>>(h, i_t, conv_w, conv_b, out);
}